// Round 1
// baseline (953.869 us; speedup 1.0000x reference)
//
#include <hip/hip_runtime.h>
#include <hip/hip_bf16.h>

#define T_TOK 4096
#define HID   1024
#define INTER 2048
#define NE    8

#define BK  32
#define LDK 40   // padded LDS row stride (elements); 80B, 16B-aligned, 2-way-bank free

typedef __attribute__((ext_vector_type(8))) short short8;
typedef __attribute__((ext_vector_type(4))) float f32x4;

__device__ __forceinline__ unsigned short f2bf(float f) {
    __hip_bfloat16 h = __float2bfloat16(f);
    return __builtin_bit_cast(unsigned short, h);
}
__device__ __forceinline__ float sigm(float x) { return 1.0f / (1.0f + __expf(-x)); }

// ---------------- cast x -> bf16 ----------------
__global__ void cast_x_kernel(const float* __restrict__ x, unsigned short* __restrict__ xb, int n4) {
    int i = blockIdx.x * blockDim.x + threadIdx.x;
    if (i >= n4) return;
    float4 v = ((const float4*)x)[i];
    ushort4 o;
    o.x = f2bf(v.x); o.y = f2bf(v.y); o.z = f2bf(v.z); o.w = f2bf(v.w);
    ((ushort4*)xb)[i] = o;
}

// ---------------- router: logits + top2 + scatter ----------------
__global__ void router_kernel(const float* __restrict__ x, const float* __restrict__ rw,
                              float* __restrict__ logits_out,
                              int* __restrict__ cnt, int* __restrict__ tok_list,
                              float* __restrict__ score_list) {
    int wave = threadIdx.x >> 6;
    int lane = threadIdx.x & 63;
    int t = blockIdx.x * 4 + wave;

    float dot[NE];
#pragma unroll
    for (int e = 0; e < NE; e++) dot[e] = 0.0f;
    const float4* xv = (const float4*)(x + (size_t)t * HID);
    const float4* wv = (const float4*)rw;
#pragma unroll
    for (int j = 0; j < 4; j++) {
        float4 xc = xv[j * 64 + lane];
#pragma unroll
        for (int e = 0; e < NE; e++) {
            float4 wc = wv[e * 256 + j * 64 + lane];
            dot[e] += xc.x * wc.x + xc.y * wc.y + xc.z * wc.z + xc.w * wc.w;
        }
    }
#pragma unroll
    for (int e = 0; e < NE; e++) {
        float v = dot[e];
        for (int m = 1; m < 64; m <<= 1) v += __shfl_xor(v, m, 64);
        dot[e] = v;
    }
    if (lane == 0) {
        float v1 = -1e30f, v2 = -1e30f; int i1 = 0, i2 = 0;
#pragma unroll
        for (int e = 0; e < NE; e++) {
            float v = dot[e];
            logits_out[(size_t)t * NE + e] = v;
            if (v > v1) { v2 = v1; i2 = i1; v1 = v; i1 = e; }
            else if (v > v2) { v2 = v; i2 = e; }
        }
        float s1 = 1.0f / (1.0f + expf(-v1));
        float s2 = 1.0f / (1.0f + expf(-v2));
        int p1 = atomicAdd(&cnt[i1], 1);
        tok_list[i1 * T_TOK + p1] = t; score_list[i1 * T_TOK + p1] = s1;
        int p2 = atomicAdd(&cnt[i2], 1);
        tok_list[i2 * T_TOK + p2] = t; score_list[i2 * T_TOK + p2] = s2;
    }
}

// ---------------- finalize: pad lists, prefix offsets ----------------
__global__ void finalize_kernel(int* __restrict__ cnt, int* __restrict__ mtiles,
                                int* __restrict__ offs, int* __restrict__ tok_list,
                                float* __restrict__ score_list) {
    __shared__ int s_cnt[NE], s_pad[NE];
    if (threadIdx.x == 0) {
        int o = 0;
        for (int e = 0; e < NE; e++) {
            int c = cnt[e];
            int p = (c + 127) & ~127;
            offs[e] = o; mtiles[e] = p >> 7;
            s_cnt[e] = c; s_pad[e] = p;
            o += p;
        }
    }
    __syncthreads();
    for (int e = 0; e < NE; e++) {
        for (int i = s_cnt[e] + (int)threadIdx.x; i < s_pad[e]; i += blockDim.x) {
            tok_list[e * T_TOK + i] = 0;
            score_list[e * T_TOK + i] = 0.0f;
        }
    }
}

// ---------------- routed GEMM1: gather-A, dual gate/up tiles, fused act ----------------
__global__ __launch_bounds__(256) void
routed_g1(const unsigned short* __restrict__ xb, const float* __restrict__ gup,
          const int* __restrict__ mtiles, const int* __restrict__ offs,
          const int* __restrict__ tok_list, const float* __restrict__ score_list,
          unsigned short* __restrict__ h) {
    int e = blockIdx.z;
    int mt = blockIdx.y;
    if (mt >= mtiles[e]) return;
    int nt = blockIdx.x;  // 0..31, 64 intermediate cols each
    const float* W = gup + (size_t)e * HID * (2 * INTER);

    __shared__ unsigned short As[128 * LDK];
    __shared__ unsigned short Bg[64 * LDK];
    __shared__ unsigned short Bu[64 * LDK];
    __shared__ int s_tok[128];
    __shared__ float s_sc[128];

    int tid = threadIdx.x, lane = tid & 63, wid = tid >> 6;
    int wm = wid >> 1, wn = wid & 1;

    if (tid < 128) {
        int slot = mt * 128 + tid;
        s_tok[tid] = tok_list[e * T_TOK + slot];
        s_sc[tid] = score_list[e * T_TOK + slot];
    }
    __syncthreads();

    f32x4 accg[4][2], accu[4][2];
#pragma unroll
    for (int i = 0; i < 4; i++)
#pragma unroll
        for (int j = 0; j < 2; j++) { accg[i][j] = (f32x4)(0.0f); accu[i][j] = (f32x4)(0.0f); }

    int colg = nt * 64;
    int colu = INTER + nt * 64;

    for (int k0 = 0; k0 < HID; k0 += BK) {
#pragma unroll
        for (int it = 0; it < 2; it++) {           // A: 128 rows x 32 k, 16B chunks
            int id = tid + it * 256;
            int row = id >> 2, c = id & 3;
            *(uint4*)(As + row * LDK + c * 8) =
                *(const uint4*)(xb + (size_t)s_tok[row] * HID + k0 + c * 8);
        }
#pragma unroll
        for (int it = 0; it < 4; it++) {           // B transpose-stage: 2 mats x 32k x 16 float4
            int id = tid + it * 256;
            int mat = id >> 9, rem = id & 511;
            int k = rem >> 4, c4 = rem & 15;
            int col = (mat ? colu : colg) + c4 * 4;
            float4 v = *(const float4*)(W + (size_t)(k0 + k) * (2 * INTER) + col);
            unsigned short* B = mat ? Bu : Bg;
            B[(c4 * 4 + 0) * LDK + k] = f2bf(v.x);
            B[(c4 * 4 + 1) * LDK + k] = f2bf(v.y);
            B[(c4 * 4 + 2) * LDK + k] = f2bf(v.z);
            B[(c4 * 4 + 3) * LDK + k] = f2bf(v.w);
        }
        __syncthreads();
        short8 af[4], bg[2], bu[2];
        int kq = (lane >> 4) * 8;
#pragma unroll
        for (int mi = 0; mi < 4; mi++)
            af[mi] = *(const short8*)(As + (wm * 64 + mi * 16 + (lane & 15)) * LDK + kq);
#pragma unroll
        for (int ni = 0; ni < 2; ni++) {
            bg[ni] = *(const short8*)(Bg + (wn * 32 + ni * 16 + (lane & 15)) * LDK + kq);
            bu[ni] = *(const short8*)(Bu + (wn * 32 + ni * 16 + (lane & 15)) * LDK + kq);
        }
#pragma unroll
        for (int mi = 0; mi < 4; mi++)
#pragma unroll
            for (int ni = 0; ni < 2; ni++) {
                accg[mi][ni] = __builtin_amdgcn_mfma_f32_16x16x32_bf16(af[mi], bg[ni], accg[mi][ni], 0, 0, 0);
                accu[mi][ni] = __builtin_amdgcn_mfma_f32_16x16x32_bf16(af[mi], bu[ni], accu[mi][ni], 0, 0, 0);
            }
        __syncthreads();
    }
    size_t rowbase = (size_t)offs[e] + (size_t)mt * 128;
    int ibase = nt * 64 + wn * 32;
#pragma unroll
    for (int mi = 0; mi < 4; mi++)
#pragma unroll
        for (int ni = 0; ni < 2; ni++)
#pragma unroll
            for (int r = 0; r < 4; r++) {
                int m = wm * 64 + mi * 16 + (lane >> 4) * 4 + r;
                int i = ibase + ni * 16 + (lane & 15);
                float s = s_sc[m];
                float g = accg[mi][ni][r] * s;
                float u = accu[mi][ni][r] * s;
                float act = u * g * sigm(g);   // u * silu(g)
                h[(rowbase + m) * INTER + i] = f2bf(act);
            }
}

// ---------------- routed GEMM2: h @ down, atomicAdd scatter into out ----------------
__global__ __launch_bounds__(256) void
routed_g2(const unsigned short* __restrict__ h, const float* __restrict__ dwn,
          const int* __restrict__ mtiles, const int* __restrict__ offs,
          const int* __restrict__ tok_list, float* __restrict__ out) {
    int e = blockIdx.z;
    int mt = blockIdx.y;
    if (mt >= mtiles[e]) return;
    int nt = blockIdx.x;  // 0..7, 128 H-cols
    const float* W = dwn + (size_t)e * INTER * HID;

    __shared__ unsigned short As[128 * LDK];
    __shared__ unsigned short Bs[128 * LDK];
    __shared__ int s_tok[128];

    int tid = threadIdx.x, lane = tid & 63, wid = tid >> 6;
    int wm = wid >> 1, wn = wid & 1;
    if (tid < 128) s_tok[tid] = tok_list[e * T_TOK + mt * 128 + tid];
    size_t rowbase = (size_t)offs[e] + (size_t)mt * 128;
    __syncthreads();

    f32x4 acc[4][4];
#pragma unroll
    for (int i = 0; i < 4; i++)
#pragma unroll
        for (int j = 0; j < 4; j++) acc[i][j] = (f32x4)(0.0f);

    for (int k0 = 0; k0 < INTER; k0 += BK) {
#pragma unroll
        for (int it = 0; it < 2; it++) {           // A: direct bf16 copy from h
            int id = tid + it * 256;
            int row = id >> 2, c = id & 3;
            *(uint4*)(As + row * LDK + c * 8) =
                *(const uint4*)(h + (rowbase + row) * INTER + k0 + c * 8);
        }
#pragma unroll
        for (int it = 0; it < 4; it++) {           // B transpose-stage: 32k x 32 float4
            int id = tid + it * 256;
            int k = id >> 5, c4 = id & 31;
            float4 v = *(const float4*)(W + (size_t)(k0 + k) * HID + nt * 128 + c4 * 4);
            Bs[(c4 * 4 + 0) * LDK + k] = f2bf(v.x);
            Bs[(c4 * 4 + 1) * LDK + k] = f2bf(v.y);
            Bs[(c4 * 4 + 2) * LDK + k] = f2bf(v.z);
            Bs[(c4 * 4 + 3) * LDK + k] = f2bf(v.w);
        }
        __syncthreads();
        short8 af[4], bf_[4];
        int kq = (lane >> 4) * 8;
#pragma unroll
        for (int mi = 0; mi < 4; mi++)
            af[mi] = *(const short8*)(As + (wm * 64 + mi * 16 + (lane & 15)) * LDK + kq);
#pragma unroll
        for (int ni = 0; ni < 4; ni++)
            bf_[ni] = *(const short8*)(Bs + (wn * 64 + ni * 16 + (lane & 15)) * LDK + kq);
#pragma unroll
        for (int mi = 0; mi < 4; mi++)
#pragma unroll
            for (int ni = 0; ni < 4; ni++)
                acc[mi][ni] = __builtin_amdgcn_mfma_f32_16x16x32_bf16(af[mi], bf_[ni], acc[mi][ni], 0, 0, 0);
        __syncthreads();
    }
#pragma unroll
    for (int mi = 0; mi < 4; mi++)
#pragma unroll
        for (int ni = 0; ni < 4; ni++)
#pragma unroll
            for (int r = 0; r < 4; r++) {
                int m = wm * 64 + mi * 16 + (lane >> 4) * 4 + r;
                int n = nt * 128 + wn * 64 + ni * 16 + (lane & 15);
                atomicAdd(&out[(size_t)s_tok[m] * HID + n], acc[mi][ni][r]);
            }
}

// ---------------- shared GEMM1: x @ {gate,up}^T, fused SwiGLU ----------------
__global__ __launch_bounds__(256) void
shared_g1(const unsigned short* __restrict__ xb, const float* __restrict__ gw,
          const float* __restrict__ uw, unsigned short* __restrict__ hs) {
    int mt = blockIdx.y;  // 0..31
    int nt = blockIdx.x;  // 0..31, 64 cols each

    __shared__ unsigned short As[128 * LDK];
    __shared__ unsigned short Bg[64 * LDK];
    __shared__ unsigned short Bu[64 * LDK];

    int tid = threadIdx.x, lane = tid & 63, wid = tid >> 6;
    int wm = wid >> 1, wn = wid & 1;

    f32x4 accg[4][2], accu[4][2];
#pragma unroll
    for (int i = 0; i < 4; i++)
#pragma unroll
        for (int j = 0; j < 2; j++) { accg[i][j] = (f32x4)(0.0f); accu[i][j] = (f32x4)(0.0f); }

    for (int k0 = 0; k0 < HID; k0 += BK) {
#pragma unroll
        for (int it = 0; it < 2; it++) {
            int id = tid + it * 256;
            int row = id >> 2, c = id & 3;
            *(uint4*)(As + row * LDK + c * 8) =
                *(const uint4*)(xb + (size_t)(mt * 128 + row) * HID + k0 + c * 8);
        }
#pragma unroll
        for (int it = 0; it < 4; it++) {           // B: NT layout, direct rows, fp32->bf16
            int id = tid + it * 256;
            int mat = id >> 9, rem = id & 511;
            int n = rem >> 3, c = rem & 7;
            const float* Wp = mat ? uw : gw;
            float4 v = *(const float4*)(Wp + (size_t)(nt * 64 + n) * HID + k0 + c * 4);
            ushort4 o;
            o.x = f2bf(v.x); o.y = f2bf(v.y); o.z = f2bf(v.z); o.w = f2bf(v.w);
            unsigned short* B = mat ? Bu : Bg;
            *(ushort4*)(B + n * LDK + c * 4) = o;
        }
        __syncthreads();
        short8 af[4], bg[2], bu[2];
        int kq = (lane >> 4) * 8;
#pragma unroll
        for (int mi = 0; mi < 4; mi++)
            af[mi] = *(const short8*)(As + (wm * 64 + mi * 16 + (lane & 15)) * LDK + kq);
#pragma unroll
        for (int ni = 0; ni < 2; ni++) {
            bg[ni] = *(const short8*)(Bg + (wn * 32 + ni * 16 + (lane & 15)) * LDK + kq);
            bu[ni] = *(const short8*)(Bu + (wn * 32 + ni * 16 + (lane & 15)) * LDK + kq);
        }
#pragma unroll
        for (int mi = 0; mi < 4; mi++)
#pragma unroll
            for (int ni = 0; ni < 2; ni++) {
                accg[mi][ni] = __builtin_amdgcn_mfma_f32_16x16x32_bf16(af[mi], bg[ni], accg[mi][ni], 0, 0, 0);
                accu[mi][ni] = __builtin_amdgcn_mfma_f32_16x16x32_bf16(af[mi], bu[ni], accu[mi][ni], 0, 0, 0);
            }
        __syncthreads();
    }
    int ibase = nt * 64 + wn * 32;
#pragma unroll
    for (int mi = 0; mi < 4; mi++)
#pragma unroll
        for (int ni = 0; ni < 2; ni++)
#pragma unroll
            for (int r = 0; r < 4; r++) {
                int m = mt * 128 + wm * 64 + mi * 16 + (lane >> 4) * 4 + r;
                int i = ibase + ni * 16 + (lane & 15);
                float g = accg[mi][ni][r];
                float u = accu[mi][ni][r];
                hs[(size_t)m * INTER + i] = f2bf(u * g * sigm(g));
            }
}

// ---------------- shared GEMM2: h_s @ down^T, plain store ----------------
__global__ __launch_bounds__(256) void
shared_g2(const unsigned short* __restrict__ hs, const float* __restrict__ dw,
          float* __restrict__ out) {
    int mt = blockIdx.y;  // 0..31
    int nt = blockIdx.x;  // 0..7

    __shared__ unsigned short As[128 * LDK];
    __shared__ unsigned short Bs[128 * LDK];

    int tid = threadIdx.x, lane = tid & 63, wid = tid >> 6;
    int wm = wid >> 1, wn = wid & 1;

    f32x4 acc[4][4];
#pragma unroll
    for (int i = 0; i < 4; i++)
#pragma unroll
        for (int j = 0; j < 4; j++) acc[i][j] = (f32x4)(0.0f);

    for (int k0 = 0; k0 < INTER; k0 += BK) {
#pragma unroll
        for (int it = 0; it < 2; it++) {
            int id = tid + it * 256;
            int row = id >> 2, c = id & 3;
            *(uint4*)(As + row * LDK + c * 8) =
                *(const uint4*)(hs + (size_t)(mt * 128 + row) * INTER + k0 + c * 8);
        }
#pragma unroll
        for (int it = 0; it < 4; it++) {           // B NT: 128 rows x 8 chunks
            int id = tid + it * 256;
            int n = id >> 3, c = id & 7;
            float4 v = *(const float4*)(dw + (size_t)(nt * 128 + n) * INTER + k0 + c * 4);
            ushort4 o;
            o.x = f2bf(v.x); o.y = f2bf(v.y); o.z = f2bf(v.z); o.w = f2bf(v.w);
            *(ushort4*)(Bs + n * LDK + c * 4) = o;
        }
        __syncthreads();
        short8 af[4], bf_[4];
        int kq = (lane >> 4) * 8;
#pragma unroll
        for (int mi = 0; mi < 4; mi++)
            af[mi] = *(const short8*)(As + (wm * 64 + mi * 16 + (lane & 15)) * LDK + kq);
#pragma unroll
        for (int ni = 0; ni < 4; ni++)
            bf_[ni] = *(const short8*)(Bs + (wn * 64 + ni * 16 + (lane & 15)) * LDK + kq);
#pragma unroll
        for (int mi = 0; mi < 4; mi++)
#pragma unroll
            for (int ni = 0; ni < 4; ni++)
                acc[mi][ni] = __builtin_amdgcn_mfma_f32_16x16x32_bf16(af[mi], bf_[ni], acc[mi][ni], 0, 0, 0);
        __syncthreads();
    }
#pragma unroll
    for (int mi = 0; mi < 4; mi++)
#pragma unroll
        for (int ni = 0; ni < 4; ni++)
#pragma unroll
            for (int r = 0; r < 4; r++) {
                int m = mt * 128 + wm * 64 + mi * 16 + (lane >> 4) * 4 + r;
                int n = nt * 128 + wn * 64 + ni * 16 + (lane & 15);
                out[(size_t)m * HID + n] = acc[mi][ni][r];
            }
}

extern "C" void kernel_launch(void* const* d_in, const int* in_sizes, int n_in,
                              void* d_out, int out_size, void* d_ws, size_t ws_size,
                              hipStream_t stream) {
    const float* x   = (const float*)d_in[0];
    const float* rw  = (const float*)d_in[1];
    const float* gup = (const float*)d_in[2];
    const float* dwn = (const float*)d_in[3];
    const float* sgw = (const float*)d_in[4];
    const float* suw = (const float*)d_in[5];
    const float* sdw = (const float*)d_in[6];
    float* out = (float*)d_out;
    float* logits = out + (size_t)T_TOK * HID;

    char* ws = (char*)d_ws;
    int* cnt    = (int*)ws;          // 8 ints
    int* mtiles = cnt + 8;           // 8 ints
    int* offs   = cnt + 16;          // 8 ints
    int* tok_list     = (int*)(ws + 128);                     // 8*4096 ints
    float* score_list = (float*)(ws + 128 + NE * T_TOK * 4);  // 8*4096 floats
    unsigned short* xb = (unsigned short*)(ws + (512 << 10));                          // 8 MB
    unsigned short* h  = (unsigned short*)(ws + (512 << 10) + (size_t)T_TOK * HID * 2); // 36 MB (9216 rows)

    hipMemsetAsync(cnt, 0, NE * sizeof(int), stream);
    cast_x_kernel<<<T_TOK * HID / 4 / 256, 256, 0, stream>>>(x, xb, T_TOK * HID / 4);
    router_kernel<<<T_TOK / 4, 256, 0, stream>>>(x, rw, logits, cnt, tok_list, score_list);
    finalize_kernel<<<1, 64, 0, stream>>>(cnt, mtiles, offs, tok_list, score_list);

    dim3 g1s(INTER / 64, T_TOK / 128);          // 32 x 32
    shared_g1<<<g1s, 256, 0, stream>>>(xb, sgw, suw, h);
    dim3 g2s(HID / 128, T_TOK / 128);           // 8 x 32
    shared_g2<<<g2s, 256, 0, stream>>>(h, sdw, out);

    dim3 g1r(INTER / 64, 32, NE);               // worst-case mtiles, early-exit
    routed_g1<<<g1r, 256, 0, stream>>>(xb, gup, mtiles, offs, tok_list, score_list, h);
    dim3 g2r(HID / 128, 32, NE);
    routed_g2<<<g2r, 256, 0, stream>>>(h, dwn, mtiles, offs, tok_list, out);
}

// Round 2
// 651.790 us; speedup vs baseline: 1.4635x; 1.4635x over previous
//
#include <hip/hip_runtime.h>
#include <hip/hip_bf16.h>

#define T_TOK 4096
#define HID   1024
#define INTER 2048
#define NE    8
#define NE1   9      // 8 routed + 1 shared expert
#define BK    32     // K-tile (bf16 elems); 64 B rows, unpadded (global_load_lds requires lane-contiguous LDS)

typedef __attribute__((ext_vector_type(8))) short short8;
typedef __attribute__((ext_vector_type(4))) float f32x4;

__device__ __forceinline__ unsigned short f2bf(float f) {
    __hip_bfloat16 h = __float2bfloat16(f);
    return __builtin_bit_cast(unsigned short, h);
}
__device__ __forceinline__ float bf2f(unsigned short u) {
    unsigned int v = ((unsigned int)u) << 16;
    return __builtin_bit_cast(float, v);
}
__device__ __forceinline__ float sigm(float x) { return 1.0f / (1.0f + __expf(-x)); }

// async global->LDS, 16B per lane. LDS dest = wave-uniform base + lane*16.
__device__ __forceinline__ void async_ld16(const void* g, void* l) {
    __builtin_amdgcn_global_load_lds(
        (const __attribute__((address_space(1))) unsigned int*)g,
        (__attribute__((address_space(3))) unsigned int*)l, 16, 0, 0);
}

// ---------------- generic fp32 -> bf16 cast ----------------
__global__ void cast_kernel(const float* __restrict__ x, unsigned short* __restrict__ xb, int n4) {
    int i = blockIdx.x * blockDim.x + threadIdx.x;
    if (i >= n4) return;
    float4 v = ((const float4*)x)[i];
    ushort4 o;
    o.x = f2bf(v.x); o.y = f2bf(v.y); o.z = f2bf(v.z); o.w = f2bf(v.w);
    ((ushort4*)xb)[i] = o;
}

// ---------------- fp32 [K][N] -> bf16 [N][K] transpose+cast ----------------
__global__ __launch_bounds__(256) void
transpose_cast(const float* __restrict__ W, unsigned short* __restrict__ Wt,
               int K, int N, size_t in_stride_e, size_t out_stride_e) {
    __shared__ float tile[64][65];
    const float* Wb = W + (size_t)blockIdx.z * in_stride_e;
    unsigned short* Wo = Wt + (size_t)blockIdx.z * out_stride_e;
    int n0 = blockIdx.x * 64, k0 = blockIdx.y * 64;
    int tid = threadIdx.x;
    int r = tid >> 4, c4 = tid & 15;
#pragma unroll
    for (int i = 0; i < 4; i++) {
        int k = i * 16 + r;
        float4 v = *(const float4*)(Wb + (size_t)(k0 + k) * N + n0 + c4 * 4);
        tile[k][c4 * 4 + 0] = v.x; tile[k][c4 * 4 + 1] = v.y;
        tile[k][c4 * 4 + 2] = v.z; tile[k][c4 * 4 + 3] = v.w;
    }
    __syncthreads();
#pragma unroll
    for (int i = 0; i < 4; i++) {
        int n = i * 16 + r;
        ushort4 o;
        o.x = f2bf(tile[c4 * 4 + 0][n]);
        o.y = f2bf(tile[c4 * 4 + 1][n]);
        o.z = f2bf(tile[c4 * 4 + 2][n]);
        o.w = f2bf(tile[c4 * 4 + 3][n]);
        *(ushort4*)(Wo + (size_t)(n0 + n) * K + k0 + c4 * 4) = o;
    }
}

// ---------------- router: logits + top2 + scatter + inverse map ----------------
__global__ void router_kernel(const float* __restrict__ x, const float* __restrict__ rw,
                              float* __restrict__ logits_out,
                              int* __restrict__ cnt, int* __restrict__ tok_list,
                              float* __restrict__ score_list, int2* __restrict__ inv) {
    int wave = threadIdx.x >> 6;
    int lane = threadIdx.x & 63;
    int t = blockIdx.x * 4 + wave;

    float dot[NE];
#pragma unroll
    for (int e = 0; e < NE; e++) dot[e] = 0.0f;
    const float4* xv = (const float4*)(x + (size_t)t * HID);
    const float4* wv = (const float4*)rw;
#pragma unroll
    for (int j = 0; j < 4; j++) {
        float4 xc = xv[j * 64 + lane];
#pragma unroll
        for (int e = 0; e < NE; e++) {
            float4 wc = wv[e * 256 + j * 64 + lane];
            dot[e] += xc.x * wc.x + xc.y * wc.y + xc.z * wc.z + xc.w * wc.w;
        }
    }
#pragma unroll
    for (int e = 0; e < NE; e++) {
        float v = dot[e];
        for (int m = 1; m < 64; m <<= 1) v += __shfl_xor(v, m, 64);
        dot[e] = v;
    }
    if (lane == 0) {
        float v1 = -1e30f, v2 = -1e30f; int i1 = 0, i2 = 0;
#pragma unroll
        for (int e = 0; e < NE; e++) {
            float v = dot[e];
            logits_out[(size_t)t * NE + e] = v;
            if (v > v1) { v2 = v1; i2 = i1; v1 = v; i1 = e; }
            else if (v > v2) { v2 = v; i2 = e; }
        }
        float s1 = 1.0f / (1.0f + expf(-v1));
        float s2 = 1.0f / (1.0f + expf(-v2));
        int p1 = atomicAdd(&cnt[i1], 1);
        tok_list[i1 * T_TOK + p1] = t; score_list[i1 * T_TOK + p1] = s1;
        int p2 = atomicAdd(&cnt[i2], 1);
        tok_list[i2 * T_TOK + p2] = t; score_list[i2 * T_TOK + p2] = s2;
        inv[t] = make_int2((i1 << 16) | p1, (i2 << 16) | p2);
    }
}

// ---------------- shared-expert list fill (expert 8: all tokens, score 1) ----------------
__global__ void fill_shared_kernel(int* __restrict__ tok_list, float* __restrict__ score_list) {
    int i = blockIdx.x * blockDim.x + threadIdx.x;
    if (i < T_TOK) {
        tok_list[NE * T_TOK + i] = i;
        score_list[NE * T_TOK + i] = 1.0f;
    }
}

// ---------------- finalize: pad lists to 128, prefix offsets over 9 experts ----------------
__global__ void finalize_kernel(const int* __restrict__ cnt, int* __restrict__ mtiles,
                                int* __restrict__ offs, int* __restrict__ tok_list,
                                float* __restrict__ score_list) {
    __shared__ int s_cnt[NE], s_pad[NE];
    if (threadIdx.x == 0) {
        int o = 0;
        for (int e = 0; e < NE1; e++) {
            int c = (e == NE) ? T_TOK : cnt[e];
            int p = (c + 127) & ~127;
            offs[e] = o; mtiles[e] = p >> 7;
            if (e < NE) { s_cnt[e] = c; s_pad[e] = p; }
            o += p;
        }
    }
    __syncthreads();
    for (int e = 0; e < NE; e++) {
        for (int i = s_cnt[e] + (int)threadIdx.x; i < s_pad[e]; i += blockDim.x) {
            tok_list[e * T_TOK + i] = 0;
            score_list[e * T_TOK + i] = 0.0f;
        }
    }
}

// ---------------- unified GEMM1: gathered x @ {gate,up}^T, fused score+SwiGLU ----------------
__global__ __launch_bounds__(256) void
moe_g1(const unsigned short* __restrict__ xb, const unsigned short* __restrict__ wg_t,
       const int* __restrict__ mtiles, const int* __restrict__ offs,
       const int* __restrict__ tok_list, const float* __restrict__ score_list,
       unsigned short* __restrict__ h) {
    int e = blockIdx.z;
    int mt = blockIdx.y;
    if (mt >= mtiles[e]) return;
    int nt = blockIdx.x;  // 0..31, 64 intermediate cols

    __shared__ unsigned short As[128 * BK];
    __shared__ unsigned short Bg[64 * BK];
    __shared__ unsigned short Bu[64 * BK];
    __shared__ int s_tok[128];
    __shared__ float s_sc[128];

    int tid = threadIdx.x, lane = tid & 63, wid = tid >> 6;
    int wm = wid >> 1, wn = wid & 1;

    if (tid < 128) {
        int slot = mt * 128 + tid;
        s_tok[tid] = tok_list[e * T_TOK + slot];
        s_sc[tid] = score_list[e * T_TOK + slot];
    }
    __syncthreads();

    const unsigned short* wg = wg_t + (size_t)e * (4096u * 1024u);
    int c8 = (tid & 3) * 8;         // short offset within 64B row chunk
    int rr = tid >> 2;              // 0..63
    const unsigned short* gA0 = xb + (size_t)s_tok[rr] * HID + c8;
    const unsigned short* gA1 = xb + (size_t)s_tok[64 + rr] * HID + c8;
    const unsigned short* gBg = wg + (size_t)(nt * 64 + rr) * HID + c8;
    const unsigned short* gBu = wg + (size_t)(INTER + nt * 64 + rr) * HID + c8;
    unsigned short* lA0 = As + wid * 64 * 8;          // wave-uniform LDS bases
    unsigned short* lA1 = As + (256 + wid * 64) * 8;
    unsigned short* lBg = Bg + wid * 64 * 8;
    unsigned short* lBu = Bu + wid * 64 * 8;

    f32x4 accg[4][2], accu[4][2];
#pragma unroll
    for (int i = 0; i < 4; i++)
#pragma unroll
        for (int j = 0; j < 2; j++) { accg[i][j] = (f32x4)(0.0f); accu[i][j] = (f32x4)(0.0f); }

    int kq = (lane >> 4) * 8;
    int mrow = lane & 15;
    for (int k0 = 0; k0 < HID; k0 += BK) {
        async_ld16(gA0 + k0, lA0);
        async_ld16(gA1 + k0, lA1);
        async_ld16(gBg + k0, lBg);
        async_ld16(gBu + k0, lBu);
        __syncthreads();
        short8 af[4], bg[2], bu[2];
#pragma unroll
        for (int mi = 0; mi < 4; mi++)
            af[mi] = *(const short8*)(As + (wm * 64 + mi * 16 + mrow) * BK + kq);
#pragma unroll
        for (int ni = 0; ni < 2; ni++) {
            bg[ni] = *(const short8*)(Bg + (wn * 32 + ni * 16 + mrow) * BK + kq);
            bu[ni] = *(const short8*)(Bu + (wn * 32 + ni * 16 + mrow) * BK + kq);
        }
#pragma unroll
        for (int mi = 0; mi < 4; mi++)
#pragma unroll
            for (int ni = 0; ni < 2; ni++) {
                accg[mi][ni] = __builtin_amdgcn_mfma_f32_16x16x32_bf16(af[mi], bg[ni], accg[mi][ni], 0, 0, 0);
                accu[mi][ni] = __builtin_amdgcn_mfma_f32_16x16x32_bf16(af[mi], bu[ni], accu[mi][ni], 0, 0, 0);
            }
        __syncthreads();
    }
    size_t rowbase = (size_t)offs[e] + (size_t)mt * 128;
    int ibase = nt * 64 + wn * 32;
#pragma unroll
    for (int mi = 0; mi < 4; mi++)
#pragma unroll
        for (int ni = 0; ni < 2; ni++)
#pragma unroll
            for (int r = 0; r < 4; r++) {
                int m = wm * 64 + mi * 16 + (lane >> 4) * 4 + r;
                int i = ibase + ni * 16 + (lane & 15);
                float s = s_sc[m];
                float g = accg[mi][ni][r] * s;
                float u = accu[mi][ni][r] * s;
                h[(rowbase + m) * INTER + i] = f2bf(u * g * sigm(g));
            }
}

// ---------------- unified GEMM2: h @ down^T -> dense r_out (no atomics) ----------------
__global__ __launch_bounds__(256) void
moe_g2(const unsigned short* __restrict__ h, const unsigned short* __restrict__ wd_t,
       const int* __restrict__ mtiles, const int* __restrict__ offs,
       unsigned short* __restrict__ r_out) {
    int e = blockIdx.z;
    int mt = blockIdx.y;
    if (mt >= mtiles[e]) return;
    int nt = blockIdx.x;  // 0..7, 128 H-cols

    __shared__ unsigned short As[128 * BK];
    __shared__ unsigned short Bs[128 * BK];

    int tid = threadIdx.x, lane = tid & 63, wid = tid >> 6;
    int wm = wid >> 1, wn = wid & 1;
    size_t rowbase = (size_t)offs[e] + (size_t)mt * 128;

    const unsigned short* wd = wd_t + (size_t)e * (1024u * 2048u);
    int c8 = (tid & 3) * 8;
    int rr = tid >> 2;
    const unsigned short* gA0 = h + (rowbase + rr) * INTER + c8;
    const unsigned short* gA1 = h + (rowbase + 64 + rr) * INTER + c8;
    const unsigned short* gB0 = wd + (size_t)(nt * 128 + rr) * INTER + c8;
    const unsigned short* gB1 = wd + (size_t)(nt * 128 + 64 + rr) * INTER + c8;
    unsigned short* lA0 = As + wid * 64 * 8;
    unsigned short* lA1 = As + (256 + wid * 64) * 8;
    unsigned short* lB0 = Bs + wid * 64 * 8;
    unsigned short* lB1 = Bs + (256 + wid * 64) * 8;

    f32x4 acc[4][4];
#pragma unroll
    for (int i = 0; i < 4; i++)
#pragma unroll
        for (int j = 0; j < 4; j++) acc[i][j] = (f32x4)(0.0f);

    int kq = (lane >> 4) * 8;
    int mrow = lane & 15;
    for (int k0 = 0; k0 < INTER; k0 += BK) {
        async_ld16(gA0 + k0, lA0);
        async_ld16(gA1 + k0, lA1);
        async_ld16(gB0 + k0, lB0);
        async_ld16(gB1 + k0, lB1);
        __syncthreads();
        short8 af[4], bf_[4];
#pragma unroll
        for (int mi = 0; mi < 4; mi++)
            af[mi] = *(const short8*)(As + (wm * 64 + mi * 16 + mrow) * BK + kq);
#pragma unroll
        for (int ni = 0; ni < 4; ni++)
            bf_[ni] = *(const short8*)(Bs + (wn * 64 + ni * 16 + mrow) * BK + kq);
#pragma unroll
        for (int mi = 0; mi < 4; mi++)
#pragma unroll
            for (int ni = 0; ni < 4; ni++)
                acc[mi][ni] = __builtin_amdgcn_mfma_f32_16x16x32_bf16(af[mi], bf_[ni], acc[mi][ni], 0, 0, 0);
        __syncthreads();
    }
#pragma unroll
    for (int mi = 0; mi < 4; mi++)
#pragma unroll
        for (int ni = 0; ni < 4; ni++)
#pragma unroll
            for (int r = 0; r < 4; r++) {
                int m = wm * 64 + mi * 16 + (lane >> 4) * 4 + r;
                int n = nt * 128 + wn * 64 + ni * 16 + (lane & 15);
                r_out[(rowbase + m) * HID + n] = f2bf(acc[mi][ni][r]);
            }
}

// ---------------- combine: out[t] = shared + two routed contributions ----------------
__global__ void combine_kernel(const unsigned short* __restrict__ r_out,
                               const int2* __restrict__ inv, const int* __restrict__ offs,
                               float* __restrict__ out) {
    int t = blockIdx.x, tid = threadIdx.x;
    int2 iv = inv[t];
    size_t r1 = (size_t)(offs[iv.x >> 16] + (iv.x & 0xffff)) * HID;
    size_t r2 = (size_t)(offs[iv.y >> 16] + (iv.y & 0xffff)) * HID;
    size_t rs = (size_t)(offs[NE] + t) * HID;
    int i = tid * 4;
    ushort4 a = *(const ushort4*)(r_out + r1 + i);
    ushort4 b = *(const ushort4*)(r_out + r2 + i);
    ushort4 c = *(const ushort4*)(r_out + rs + i);
    float4 o;
    o.x = bf2f(a.x) + bf2f(b.x) + bf2f(c.x);
    o.y = bf2f(a.y) + bf2f(b.y) + bf2f(c.y);
    o.z = bf2f(a.z) + bf2f(b.z) + bf2f(c.z);
    o.w = bf2f(a.w) + bf2f(b.w) + bf2f(c.w);
    *(float4*)(out + (size_t)t * HID + i) = o;
}

extern "C" void kernel_launch(void* const* d_in, const int* in_sizes, int n_in,
                              void* d_out, int out_size, void* d_ws, size_t ws_size,
                              hipStream_t stream) {
    const float* x   = (const float*)d_in[0];
    const float* rw  = (const float*)d_in[1];
    const float* gup = (const float*)d_in[2];
    const float* dwn = (const float*)d_in[3];
    const float* sgw = (const float*)d_in[4];
    const float* suw = (const float*)d_in[5];
    const float* sdw = (const float*)d_in[6];
    float* out = (float*)d_out;
    float* logits = out + (size_t)T_TOK * HID;

    char* ws = (char*)d_ws;
    int*   cnt        = (int*)(ws + 0);
    int*   mtiles     = (int*)(ws + 64);
    int*   offs       = (int*)(ws + 128);
    int2*  inv        = (int2*)(ws + 4096);                 // 32 KB
    int*   tok_list   = (int*)(ws + 65536);                 // 9*4096*4 = 144 KB
    float* score_list = (float*)(ws + 212992);              // 144 KB
    unsigned short* xb      = (unsigned short*)(ws + 524288);        // 8 MB
    unsigned short* w_gup_t = (unsigned short*)(ws + 9437184);       // 9*4096*1024*2 = 72 MB
    unsigned short* w_dwn_t = (unsigned short*)(ws + 89128960);      // 9*1024*2048*2 = 36 MB
    unsigned short* h       = (unsigned short*)(ws + 134217728);     // 13312*2048*2 = 52 MB
    unsigned short* r_out   = (unsigned short*)(ws + 201326592);     // 13312*1024*2 = 26 MB

    hipMemsetAsync(cnt, 0, NE * sizeof(int), stream);

    // weight prep: transpose routed weights to bf16 [N][K]; shared already [N][K]
    {
        dim3 g(4096 / 64, 1024 / 64, NE);
        transpose_cast<<<g, 256, 0, stream>>>(gup, w_gup_t, 1024, 4096,
                                              (size_t)1024 * 4096, (size_t)4096 * 1024);
    }
    {
        dim3 g(1024 / 64, 2048 / 64, NE);
        transpose_cast<<<g, 256, 0, stream>>>(dwn, w_dwn_t, 2048, 1024,
                                              (size_t)2048 * 1024, (size_t)1024 * 2048);
    }
    unsigned short* wg8 = w_gup_t + (size_t)NE * 4096 * 1024;
    cast_kernel<<<(2048 * 1024 / 4 + 255) / 256, 256, 0, stream>>>(sgw, wg8, 2048 * 1024 / 4);
    cast_kernel<<<(2048 * 1024 / 4 + 255) / 256, 256, 0, stream>>>(suw, wg8 + 2048 * 1024, 2048 * 1024 / 4);
    cast_kernel<<<(1024 * 2048 / 4 + 255) / 256, 256, 0, stream>>>(sdw, w_dwn_t + (size_t)NE * 1024 * 2048, 1024 * 2048 / 4);
    cast_kernel<<<(T_TOK * HID / 4 + 255) / 256, 256, 0, stream>>>(x, xb, T_TOK * HID / 4);

    router_kernel<<<T_TOK / 4, 256, 0, stream>>>(x, rw, logits, cnt, tok_list, score_list, inv);
    fill_shared_kernel<<<T_TOK / 256, 256, 0, stream>>>(tok_list, score_list);
    finalize_kernel<<<1, 128, 0, stream>>>(cnt, mtiles, offs, tok_list, score_list);

    dim3 g1(INTER / 64, 64, NE1);   // early-exit on mtiles
    moe_g1<<<g1, 256, 0, stream>>>(xb, w_gup_t, mtiles, offs, tok_list, score_list, h);
    dim3 g2(HID / 128, 64, NE1);
    moe_g2<<<g2, 256, 0, stream>>>(h, w_dwn_t, mtiles, offs, r_out);
    combine_kernel<<<T_TOK, 256, 0, stream>>>(r_out, inv, offs, out);
}

// Round 3
// 637.271 us; speedup vs baseline: 1.4968x; 1.0228x over previous
//
#include <hip/hip_runtime.h>
#include <hip/hip_bf16.h>

#define T_TOK 4096
#define HID   1024
#define INTER 2048
#define NE    8
#define NE1   9      // 8 routed + 1 shared expert
#define BK    64     // K-tile (bf16 elems); XOR-swizzled chunks, global_load_lds staged
#define MAXT  104    // max 128-row m-tiles: <=71 routed (8192/128+7) + 32 shared

typedef __attribute__((ext_vector_type(8))) short short8;
typedef __attribute__((ext_vector_type(8))) unsigned short ushort8v;
typedef __attribute__((ext_vector_type(4))) float f32x4;

__device__ __forceinline__ unsigned short f2bf(float f) {
    __hip_bfloat16 h = __float2bfloat16(f);
    return __builtin_bit_cast(unsigned short, h);
}
__device__ __forceinline__ float bf2f(unsigned short u) {
    unsigned int v = ((unsigned int)u) << 16;
    return __builtin_bit_cast(float, v);
}
__device__ __forceinline__ float sigm(float x) { return 1.0f / (1.0f + __expf(-x)); }

// async global->LDS, 16B per lane. LDS dest = wave-uniform base + lane*16.
__device__ __forceinline__ void async_ld16(const void* g, void* l) {
    __builtin_amdgcn_global_load_lds(
        (const __attribute__((address_space(1))) unsigned int*)g,
        (__attribute__((address_space(3))) unsigned int*)l, 16, 0, 0);
}

// ---------------- generic fp32 -> bf16 cast ----------------
__global__ void cast_kernel(const float* __restrict__ x, unsigned short* __restrict__ xb, int n4) {
    int i = blockIdx.x * blockDim.x + threadIdx.x;
    if (i >= n4) return;
    float4 v = ((const float4*)x)[i];
    ushort4 o;
    o.x = f2bf(v.x); o.y = f2bf(v.y); o.z = f2bf(v.z); o.w = f2bf(v.w);
    ((ushort4*)xb)[i] = o;
}

// ---------- fp32 [K][N] -> bf16 [N][K] transpose+cast, 128k x 64n tiles ----------
__global__ __launch_bounds__(256) void
transpose_cast(const float* __restrict__ W, unsigned short* __restrict__ Wt,
               int K, int N, size_t in_stride_e, size_t out_stride_e) {
    __shared__ float tile[128][65];
    const float* Wb = W + (size_t)blockIdx.z * in_stride_e;
    unsigned short* Wo = Wt + (size_t)blockIdx.z * out_stride_e;
    int n0 = blockIdx.x * 64, k0 = blockIdx.y * 128;
    int tid = threadIdx.x;
    int r = tid >> 4, c = tid & 15;
#pragma unroll
    for (int i = 0; i < 8; i++) {              // read: 128 k-rows x 64 n (256B segs)
        int k = i * 16 + r;
        float4 v = *(const float4*)(Wb + (size_t)(k0 + k) * N + n0 + c * 4);
        tile[k][c * 4 + 0] = v.x; tile[k][c * 4 + 1] = v.y;
        tile[k][c * 4 + 2] = v.z; tile[k][c * 4 + 3] = v.w;
    }
    __syncthreads();
#pragma unroll
    for (int i = 0; i < 4; i++) {              // write: 64 n-rows x 128 k (256B segs)
        int n = i * 16 + r;
        ushort8v o;
#pragma unroll
        for (int j = 0; j < 8; j++) o[j] = f2bf(tile[c * 8 + j][n]);
        *(ushort8v*)(Wo + (size_t)(n0 + n) * K + k0 + c * 8) = o;
    }
}

// ---------------- router: logits + top2 + scatter + inverse map ----------------
__global__ void router_kernel(const float* __restrict__ x, const float* __restrict__ rw,
                              float* __restrict__ logits_out,
                              int* __restrict__ cnt, int* __restrict__ tok_list,
                              float* __restrict__ score_list, int2* __restrict__ inv) {
    int wave = threadIdx.x >> 6;
    int lane = threadIdx.x & 63;
    int t = blockIdx.x * 4 + wave;

    float dot[NE];
#pragma unroll
    for (int e = 0; e < NE; e++) dot[e] = 0.0f;
    const float4* xv = (const float4*)(x + (size_t)t * HID);
    const float4* wv = (const float4*)rw;
#pragma unroll
    for (int j = 0; j < 4; j++) {
        float4 xc = xv[j * 64 + lane];
#pragma unroll
        for (int e = 0; e < NE; e++) {
            float4 wc = wv[e * 256 + j * 64 + lane];
            dot[e] += xc.x * wc.x + xc.y * wc.y + xc.z * wc.z + xc.w * wc.w;
        }
    }
#pragma unroll
    for (int e = 0; e < NE; e++) {
        float v = dot[e];
        for (int m = 1; m < 64; m <<= 1) v += __shfl_xor(v, m, 64);
        dot[e] = v;
    }
    if (lane == 0) {
        float v1 = -1e30f, v2 = -1e30f; int i1 = 0, i2 = 0;
#pragma unroll
        for (int e = 0; e < NE; e++) {
            float v = dot[e];
            logits_out[(size_t)t * NE + e] = v;
            if (v > v1) { v2 = v1; i2 = i1; v1 = v; i1 = e; }
            else if (v > v2) { v2 = v; i2 = e; }
        }
        float s1 = 1.0f / (1.0f + expf(-v1));
        float s2 = 1.0f / (1.0f + expf(-v2));
        int p1 = atomicAdd(&cnt[i1], 1);
        tok_list[i1 * T_TOK + p1] = t; score_list[i1 * T_TOK + p1] = s1;
        int p2 = atomicAdd(&cnt[i2], 1);
        tok_list[i2 * T_TOK + p2] = t; score_list[i2 * T_TOK + p2] = s2;
        inv[t] = make_int2((i1 << 16) | p1, (i2 << 16) | p2);
    }
}

// ---------------- shared-expert list fill (expert 8: all tokens, score 1) ----------------
__global__ void fill_shared_kernel(int* __restrict__ tok_list, float* __restrict__ score_list) {
    int i = blockIdx.x * blockDim.x + threadIdx.x;
    if (i < T_TOK) {
        tok_list[NE * T_TOK + i] = i;
        score_list[NE * T_TOK + i] = 1.0f;
    }
}

// -------- finalize: pad lists, prefix offsets, build dense tile table --------
__global__ void finalize_kernel(const int* __restrict__ cnt, int* __restrict__ offs,
                                int* __restrict__ tiletab,
                                int* __restrict__ tok_list, float* __restrict__ score_list) {
    __shared__ int s_cnt[NE], s_pad[NE];
    if (threadIdx.x == 0) {
        int o = 0, nt = 0;
        for (int e = 0; e < NE1; e++) {
            int c = (e == NE) ? T_TOK : cnt[e];
            int p = (c + 127) & ~127;
            offs[e] = o;
            for (int m = 0; m < (p >> 7); m++) tiletab[nt++] = (e << 8) | m;
            if (e < NE) { s_cnt[e] = c; s_pad[e] = p; }
            o += p;
        }
        for (; nt < MAXT; nt++) tiletab[nt] = -1;
    }
    __syncthreads();
    for (int e = 0; e < NE; e++) {
        for (int i = s_cnt[e] + (int)threadIdx.x; i < s_pad[e]; i += blockDim.x) {
            tok_list[e * T_TOK + i] = 0;
            score_list[e * T_TOK + i] = 0.0f;
        }
    }
}

// ---------------- unified GEMM1: gathered x @ {gate,up}^T, fused score+SwiGLU ----------------
__global__ __launch_bounds__(256) void
moe_g1(const unsigned short* __restrict__ xb, const unsigned short* __restrict__ wg_t,
       const int* __restrict__ tiletab, const int* __restrict__ offs,
       const int* __restrict__ tok_list, const float* __restrict__ score_list,
       unsigned short* __restrict__ h) {
    int tt = tiletab[blockIdx.y];
    if (tt < 0) return;
    int e = tt >> 8, mt = tt & 255;
    int nt = blockIdx.x;  // 0..31, 64 intermediate cols

    __shared__ unsigned short As[128 * BK];   // 16 KB
    __shared__ unsigned short Bg[64 * BK];    // 8 KB
    __shared__ unsigned short Bu[64 * BK];    // 8 KB
    __shared__ int s_tok[128];
    __shared__ float s_sc[128];

    int tid = threadIdx.x, lane = tid & 63;
    int wid = tid >> 6, wm = wid >> 1, wn = wid & 1;

    if (tid < 128) {
        int slot = mt * 128 + tid;
        s_tok[tid] = tok_list[e * T_TOK + slot];
        s_sc[tid] = score_list[e * T_TOK + slot];
    }
    __syncthreads();

    const unsigned short* wg = wg_t + (size_t)e * (4096u * 1024u);
    int rsub = tid >> 3;                       // 0..31 staging row within issue
    int csw = (tid & 7) ^ (rsub & 7);          // XOR-swizzled source chunk
    const unsigned short* pA[4];
#pragma unroll
    for (int i = 0; i < 4; i++)
        pA[i] = xb + (size_t)s_tok[i * 32 + rsub] * HID + csw * 8;
    const unsigned short* pBg[2];
    const unsigned short* pBu[2];
#pragma unroll
    for (int i = 0; i < 2; i++) {
        pBg[i] = wg + (size_t)(nt * 64 + i * 32 + rsub) * HID + csw * 8;
        pBu[i] = wg + (size_t)(INTER + nt * 64 + i * 32 + rsub) * HID + csw * 8;
    }
    unsigned short* lA = As + tid * 8;         // + i*2048 per issue
    unsigned short* lBg = Bg + tid * 8;
    unsigned short* lBu = Bu + tid * 8;

    f32x4 accg[4][2], accu[4][2];
#pragma unroll
    for (int i = 0; i < 4; i++)
#pragma unroll
        for (int j = 0; j < 2; j++) { accg[i][j] = (f32x4)(0.0f); accu[i][j] = (f32x4)(0.0f); }

    int mrow = lane & 15, q = lane >> 4, x7 = lane & 7;
    for (int k0 = 0; k0 < HID; k0 += BK) {
#pragma unroll
        for (int i = 0; i < 4; i++) async_ld16(pA[i] + k0, lA + i * 2048);
#pragma unroll
        for (int i = 0; i < 2; i++) {
            async_ld16(pBg[i] + k0, lBg + i * 2048);
            async_ld16(pBu[i] + k0, lBu + i * 2048);
        }
        __syncthreads();
#pragma unroll
        for (int ksub = 0; ksub < 2; ksub++) {
            int ch = ((ksub * 4 + q) ^ x7) * 8;
            short8 af[4], bg[2], bu[2];
#pragma unroll
            for (int mi = 0; mi < 4; mi++)
                af[mi] = *(const short8*)(As + (wm * 64 + mi * 16 + mrow) * BK + ch);
#pragma unroll
            for (int ni = 0; ni < 2; ni++) {
                bg[ni] = *(const short8*)(Bg + (wn * 32 + ni * 16 + mrow) * BK + ch);
                bu[ni] = *(const short8*)(Bu + (wn * 32 + ni * 16 + mrow) * BK + ch);
            }
#pragma unroll
            for (int mi = 0; mi < 4; mi++)
#pragma unroll
                for (int ni = 0; ni < 2; ni++) {
                    accg[mi][ni] = __builtin_amdgcn_mfma_f32_16x16x32_bf16(af[mi], bg[ni], accg[mi][ni], 0, 0, 0);
                    accu[mi][ni] = __builtin_amdgcn_mfma_f32_16x16x32_bf16(af[mi], bu[ni], accu[mi][ni], 0, 0, 0);
                }
        }
        __syncthreads();
    }
    size_t rowbase = (size_t)offs[e] + (size_t)mt * 128;
    int ibase = nt * 64 + wn * 32;
#pragma unroll
    for (int mi = 0; mi < 4; mi++)
#pragma unroll
        for (int ni = 0; ni < 2; ni++)
#pragma unroll
            for (int r = 0; r < 4; r++) {
                int m = wm * 64 + mi * 16 + (lane >> 4) * 4 + r;
                int i = ibase + ni * 16 + (lane & 15);
                float s = s_sc[m];
                float g = accg[mi][ni][r] * s;
                float u = accu[mi][ni][r] * s;
                h[(rowbase + m) * INTER + i] = f2bf(u * g * sigm(g));
            }
}

// ---------------- unified GEMM2: h @ down^T -> dense r_out (no atomics) ----------------
__global__ __launch_bounds__(256) void
moe_g2(const unsigned short* __restrict__ h, const unsigned short* __restrict__ wd_t,
       const int* __restrict__ tiletab, const int* __restrict__ offs,
       unsigned short* __restrict__ r_out) {
    int tt = tiletab[blockIdx.y];
    if (tt < 0) return;
    int e = tt >> 8, mt = tt & 255;
    int nt = blockIdx.x;  // 0..7, 128 H-cols

    __shared__ unsigned short As[128 * BK];   // 16 KB
    __shared__ unsigned short Bs[128 * BK];   // 16 KB

    int tid = threadIdx.x, lane = tid & 63;
    int wid = tid >> 6, wm = wid >> 1, wn = wid & 1;
    size_t rowbase = (size_t)offs[e] + (size_t)mt * 128;

    const unsigned short* wd = wd_t + (size_t)e * (1024u * 2048u);
    int rsub = tid >> 3;
    int csw = (tid & 7) ^ (rsub & 7);
    const unsigned short* pA[4];
    const unsigned short* pB[4];
#pragma unroll
    for (int i = 0; i < 4; i++) {
        pA[i] = h + (rowbase + i * 32 + rsub) * INTER + csw * 8;
        pB[i] = wd + (size_t)(nt * 128 + i * 32 + rsub) * INTER + csw * 8;
    }
    unsigned short* lA = As + tid * 8;
    unsigned short* lB = Bs + tid * 8;

    f32x4 acc[4][4];
#pragma unroll
    for (int i = 0; i < 4; i++)
#pragma unroll
        for (int j = 0; j < 4; j++) acc[i][j] = (f32x4)(0.0f);

    int mrow = lane & 15, q = lane >> 4, x7 = lane & 7;
    for (int k0 = 0; k0 < INTER; k0 += BK) {
#pragma unroll
        for (int i = 0; i < 4; i++) {
            async_ld16(pA[i] + k0, lA + i * 2048);
            async_ld16(pB[i] + k0, lB + i * 2048);
        }
        __syncthreads();
#pragma unroll
        for (int ksub = 0; ksub < 2; ksub++) {
            int ch = ((ksub * 4 + q) ^ x7) * 8;
            short8 af[4], bf_[4];
#pragma unroll
            for (int mi = 0; mi < 4; mi++)
                af[mi] = *(const short8*)(As + (wm * 64 + mi * 16 + mrow) * BK + ch);
#pragma unroll
            for (int ni = 0; ni < 4; ni++)
                bf_[ni] = *(const short8*)(Bs + (wn * 64 + ni * 16 + mrow) * BK + ch);
#pragma unroll
            for (int mi = 0; mi < 4; mi++)
#pragma unroll
                for (int ni = 0; ni < 4; ni++)
                    acc[mi][ni] = __builtin_amdgcn_mfma_f32_16x16x32_bf16(af[mi], bf_[ni], acc[mi][ni], 0, 0, 0);
        }
        __syncthreads();
    }
#pragma unroll
    for (int mi = 0; mi < 4; mi++)
#pragma unroll
        for (int ni = 0; ni < 4; ni++)
#pragma unroll
            for (int r = 0; r < 4; r++) {
                int m = wm * 64 + mi * 16 + (lane >> 4) * 4 + r;
                int n = nt * 128 + wn * 64 + ni * 16 + (lane & 15);
                r_out[(rowbase + m) * HID + n] = f2bf(acc[mi][ni][r]);
            }
}

// ---------------- combine: out[t] = shared + two routed contributions ----------------
__global__ void combine_kernel(const unsigned short* __restrict__ r_out,
                               const int2* __restrict__ inv, const int* __restrict__ offs,
                               float* __restrict__ out) {
    int t = blockIdx.x, tid = threadIdx.x;
    int2 iv = inv[t];
    size_t r1 = (size_t)(offs[iv.x >> 16] + (iv.x & 0xffff)) * HID;
    size_t r2 = (size_t)(offs[iv.y >> 16] + (iv.y & 0xffff)) * HID;
    size_t rs = (size_t)(offs[NE] + t) * HID;
    int i = tid * 4;
    ushort4 a = *(const ushort4*)(r_out + r1 + i);
    ushort4 b = *(const ushort4*)(r_out + r2 + i);
    ushort4 c = *(const ushort4*)(r_out + rs + i);
    float4 o;
    o.x = bf2f(a.x) + bf2f(b.x) + bf2f(c.x);
    o.y = bf2f(a.y) + bf2f(b.y) + bf2f(c.y);
    o.z = bf2f(a.z) + bf2f(b.z) + bf2f(c.z);
    o.w = bf2f(a.w) + bf2f(b.w) + bf2f(c.w);
    *(float4*)(out + (size_t)t * HID + i) = o;
}

extern "C" void kernel_launch(void* const* d_in, const int* in_sizes, int n_in,
                              void* d_out, int out_size, void* d_ws, size_t ws_size,
                              hipStream_t stream) {
    const float* x   = (const float*)d_in[0];
    const float* rw  = (const float*)d_in[1];
    const float* gup = (const float*)d_in[2];
    const float* dwn = (const float*)d_in[3];
    const float* sgw = (const float*)d_in[4];
    const float* suw = (const float*)d_in[5];
    const float* sdw = (const float*)d_in[6];
    float* out = (float*)d_out;
    float* logits = out + (size_t)T_TOK * HID;

    char* ws = (char*)d_ws;
    int*   cnt        = (int*)(ws + 0);
    int*   offs       = (int*)(ws + 64);
    int*   tiletab    = (int*)(ws + 128);                   // 104 ints
    int2*  inv        = (int2*)(ws + 4096);                 // 32 KB
    int*   tok_list   = (int*)(ws + 65536);                 // 144 KB
    float* score_list = (float*)(ws + 212992);              // 144 KB
    unsigned short* xb      = (unsigned short*)(ws + 524288);        // 8 MB
    unsigned short* w_gup_t = (unsigned short*)(ws + 9437184);       // 72 MB
    unsigned short* w_dwn_t = (unsigned short*)(ws + 89128960);      // 36 MB
    unsigned short* h       = (unsigned short*)(ws + 134217728);     // 52 MB
    unsigned short* r_out   = (unsigned short*)(ws + 201326592);     // 26 MB

    hipMemsetAsync(cnt, 0, NE * sizeof(int), stream);

    // weight prep: transpose routed weights to bf16 [N][K]; shared already [N][K]
    {
        dim3 g(4096 / 64, 1024 / 128, NE);
        transpose_cast<<<g, 256, 0, stream>>>(gup, w_gup_t, 1024, 4096,
                                              (size_t)1024 * 4096, (size_t)4096 * 1024);
    }
    {
        dim3 g(1024 / 64, 2048 / 128, NE);
        transpose_cast<<<g, 256, 0, stream>>>(dwn, w_dwn_t, 2048, 1024,
                                              (size_t)2048 * 1024, (size_t)1024 * 2048);
    }
    unsigned short* wg8 = w_gup_t + (size_t)NE * 4096 * 1024;
    cast_kernel<<<(2048 * 1024 / 4 + 255) / 256, 256, 0, stream>>>(sgw, wg8, 2048 * 1024 / 4);
    cast_kernel<<<(2048 * 1024 / 4 + 255) / 256, 256, 0, stream>>>(suw, wg8 + 2048 * 1024, 2048 * 1024 / 4);
    cast_kernel<<<(1024 * 2048 / 4 + 255) / 256, 256, 0, stream>>>(sdw, w_dwn_t + (size_t)NE * 1024 * 2048, 1024 * 2048 / 4);
    cast_kernel<<<(T_TOK * HID / 4 + 255) / 256, 256, 0, stream>>>(x, xb, T_TOK * HID / 4);

    router_kernel<<<T_TOK / 4, 256, 0, stream>>>(x, rw, logits, cnt, tok_list, score_list, inv);
    fill_shared_kernel<<<T_TOK / 256, 256, 0, stream>>>(tok_list, score_list);
    finalize_kernel<<<1, 128, 0, stream>>>(cnt, offs, tiletab, tok_list, score_list);

    dim3 g1(INTER / 64, MAXT);
    moe_g1<<<g1, 256, 0, stream>>>(xb, w_gup_t, tiletab, offs, tok_list, score_list, h);
    dim3 g2(HID / 128, MAXT);
    moe_g2<<<g2, 256, 0, stream>>>(h, w_dwn_t, tiletab, offs, r_out);
    combine_kernel<<<T_TOK, 256, 0, stream>>>(r_out, inv, offs, out);
}